// Round 1
// baseline (4155.680 us; speedup 1.0000x reference)
//
#include <hip/hip_runtime.h>
#include <hip/hip_fp16.h>

#define B_ 128
#define T_ 64
#define I_ 128
#define H_ 256
#define UF 6
#define EPSF 1e-8f

static __device__ __forceinline__ float rcpf(float x) { return __builtin_amdgcn_rcpf(x); }

// ---------------- K0: pack params to fp16 (A = -sigma*log2e, B = sigma*mu*log2e, WE = w*erev)
__global__ __launch_bounds__(256) void pack_params(
    const float* __restrict__ smu, const float* __restrict__ ssig,
    const float* __restrict__ sw,  const float* __restrict__ serev,
    const float* __restrict__ imu, const float* __restrict__ isig,
    const float* __restrict__ iw,  const float* __restrict__ ierev,
    unsigned* __restrict__ AB_s, unsigned short* __restrict__ WE_s,
    unsigned* __restrict__ AB_i, unsigned short* __restrict__ WE_i)
{
    const float L2E = 1.4426950408889634f;
    int idx = blockIdx.x * 256 + threadIdx.x;   // grid = 256*256 = 65536 = H*H
    {
        float s = isig[idx], m = imu[idx], w = iw[idx], e = ierev[idx];
        unsigned a = (unsigned)__half_as_ushort(__float2half_rn(-s * L2E));
        unsigned b = (unsigned)__half_as_ushort(__float2half_rn(s * m * L2E));
        AB_i[idx] = a | (b << 16);
        WE_i[idx] = __half_as_ushort(__float2half_rn(w * e));
    }
    if (idx < I_ * H_) {
        float s = ssig[idx], m = smu[idx], w = sw[idx], e = serev[idx];
        unsigned a = (unsigned)__half_as_ushort(__float2half_rn(-s * L2E));
        unsigned b = (unsigned)__half_as_ushort(__float2half_rn(s * m * L2E));
        AB_s[idx] = a | (b << 16);
        WE_s[idx] = __half_as_ushort(__float2half_rn(w * e));
    }
}

// ---------------- K1: recurrent LTC. One block per batch element.
// 1024 threads = (j in [0,256)) x (c in [0,4)): thread sums gates over its i-chunk.
__global__ __launch_bounds__(1024) void ltc_rec(
    const float* __restrict__ x, const float* __restrict__ in_w, const float* __restrict__ in_b,
    const unsigned* __restrict__ AB_s, const unsigned short* __restrict__ WE_s,
    const unsigned* __restrict__ AB_i, const unsigned short* __restrict__ WE_i,
    const float* __restrict__ vleak, const float* __restrict__ gleak, const float* __restrict__ cm,
    const float* __restrict__ out_w, const float* __restrict__ out_b,
    float* __restrict__ out, float* __restrict__ hT)
{
    __shared__ float Vs[H_];
    __shared__ float xs[I_];
    __shared__ float rn[4][H_];
    __shared__ float rd[4][H_];
    __shared__ float sn[H_], sd[H_];

    const int b   = blockIdx.x;
    const int tid = threadIdx.x;
    const int j   = tid & (H_ - 1);
    const int c   = tid >> 8;            // 0..3, wave-uniform

    const float cmt  = cm[j] * (float)UF;
    const float gl   = gleak[j];
    const float glvl = gl * vleak[j];
    const float dc   = cmt + gl + EPSF;
    const float owj  = out_w[j], obj = out_b[j];

    float iwv = 0.f, ibv = 0.f;
    if (tid < I_) { iwv = in_w[tid]; ibv = in_b[tid]; }

    if (tid < H_) Vs[tid] = 0.f;

    const float* xrow = x + (size_t)b * T_ * I_;

    for (int t = 0; t < T_; ++t) {
        if (tid < I_) xs[tid] = fmaf(xrow[t * I_ + tid], iwv, ibv);
        __syncthreads();                               // xs ready (also Vs=0 on t==0)

        // ---- sensing sums: 32 i's per thread
        float pn = 0.f, pd = 0.f;
        {
            const int i0 = c * 32;
            #pragma unroll 8
            for (int ii = 0; ii < 32; ++ii) {
                const int i = i0 + ii;
                unsigned ab = AB_s[i * H_ + j];
                float wv = __half2float(__ushort_as_half(WE_s[i * H_ + j]));
                float xv = xs[i];
                float A  = __half2float(__ushort_as_half((unsigned short)(ab & 0xffffu)));
                float Bv = __half2float(__ushort_as_half((unsigned short)(ab >> 16)));
                float r  = rcpf(1.f + exp2f(fmaf(A, xv, Bv)));
                pn = fmaf(wv, r, pn);
                pd = fmaf(fabsf(wv), r, pd);
            }
        }
        rn[c][j] = pn; rd[c][j] = pd;
        __syncthreads();                               // sensing partials ready
        if (c == 0) {
            sn[j] = rn[0][j] + rn[1][j] + rn[2][j] + rn[3][j];
            sd[j] = rd[0][j] + rd[1][j] + rd[2][j] + rd[3][j];
        }
        __syncthreads();                               // sn/sd ready, rn/rd free

        // ---- 6 unfolds
        for (int u = 0; u < UF; ++u) {
            float nm = 0.f, dn = 0.f;
            const int i0 = c * 64;
            #pragma unroll 8
            for (int ii = 0; ii < 64; ++ii) {
                const int i = i0 + ii;
                unsigned ab = AB_i[i * H_ + j];
                float wv = __half2float(__ushort_as_half(WE_i[i * H_ + j]));
                float vv = Vs[i];
                float A  = __half2float(__ushort_as_half((unsigned short)(ab & 0xffffu)));
                float Bv = __half2float(__ushort_as_half((unsigned short)(ab >> 16)));
                float r  = rcpf(1.f + exp2f(fmaf(A, vv, Bv)));
                nm = fmaf(wv, r, nm);
                dn = fmaf(fabsf(wv), r, dn);
            }
            rn[c][j] = nm; rd[c][j] = dn;
            __syncthreads();                           // partials ready; all Vs reads done
            if (c == 0) {
                float N = rn[0][j] + rn[1][j] + rn[2][j] + rn[3][j] + sn[j];
                float D = rd[0][j] + rd[1][j] + rd[2][j] + rd[3][j] + sd[j];
                Vs[j] = (fmaf(Vs[j], cmt, glvl) + N) * rcpf(D + dc);
            }
            __syncthreads();                           // Vs ready for next unfold
        }

        if (c == 0) out[((size_t)b * T_ + t) * H_ + j] = fmaf(Vs[j], owj, obj);
    }
    if (c == 0) hT[(size_t)b * H_ + j] = Vs[j];
}

extern "C" void kernel_launch(void* const* d_in, const int* in_sizes, int n_in,
                              void* d_out, int out_size, void* d_ws, size_t ws_size,
                              hipStream_t stream) {
    const float* x     = (const float*)d_in[0];
    const float* in_w  = (const float*)d_in[1];
    const float* in_b  = (const float*)d_in[2];
    const float* smu   = (const float*)d_in[3];
    const float* ssig  = (const float*)d_in[4];
    const float* sw    = (const float*)d_in[5];
    const float* serev = (const float*)d_in[6];
    const float* imu   = (const float*)d_in[7];
    const float* isig  = (const float*)d_in[8];
    const float* iw    = (const float*)d_in[9];
    const float* ierev = (const float*)d_in[10];
    const float* vleak = (const float*)d_in[11];
    const float* gleak = (const float*)d_in[12];
    const float* cmv   = (const float*)d_in[13];
    const float* ow    = (const float*)d_in[14];
    const float* ob    = (const float*)d_in[15];

    float* out = (float*)d_out;                 // [B, T, H]
    float* hT  = out + (size_t)B_ * T_ * H_;    // [B, H]

    char* w = (char*)d_ws;
    unsigned*       AB_i = (unsigned*)(w);                       // 256 KB
    unsigned short* WE_i = (unsigned short*)(w + 262144);        // 128 KB
    unsigned*       AB_s = (unsigned*)(w + 262144 + 131072);     // 128 KB
    unsigned short* WE_s = (unsigned short*)(w + 262144 + 131072 + 131072); // 64 KB

    pack_params<<<dim3(H_ * H_ / 256), dim3(256), 0, stream>>>(
        smu, ssig, sw, serev, imu, isig, iw, ierev, AB_s, WE_s, AB_i, WE_i);

    ltc_rec<<<dim3(B_), dim3(1024), 0, stream>>>(
        x, in_w, in_b, AB_s, WE_s, AB_i, WE_i, vleak, gleak, cmv, ow, ob, out, hT);
}

// Round 2
// 2350.486 us; speedup vs baseline: 1.7680x; 1.7680x over previous
//
#include <hip/hip_runtime.h>
#include <hip/hip_fp16.h>

#define B_ 128
#define T_ 64
#define I_ 128
#define H_ 256
#define UF 6
#define EPSF 1e-8f
#define NBLK 256

static __device__ __forceinline__ float rcpf(float x) { return __builtin_amdgcn_rcpf(x); }
static __device__ __forceinline__ float h2f_lo(unsigned u) {
    return __half2float(__ushort_as_half((unsigned short)(u & 0xffffu)));
}
static __device__ __forceinline__ float h2f_hi(unsigned u) {
    return __half2float(__ushort_as_half((unsigned short)(u >> 16)));
}

// ---------------- K0: pack params to fp16, zero sync flags.
// A = -sigma*log2e, B = sigma*mu*log2e, W = w*erev (|W| = w since erev = +-1)
__global__ __launch_bounds__(256) void pack_params(
    const float* __restrict__ smu, const float* __restrict__ ssig,
    const float* __restrict__ sw,  const float* __restrict__ serev,
    const float* __restrict__ imu, const float* __restrict__ isig,
    const float* __restrict__ iw,  const float* __restrict__ ierev,
    unsigned* __restrict__ AB_s, unsigned short* __restrict__ WE_s,
    unsigned* __restrict__ AB_i, unsigned* __restrict__ W2_i, int* __restrict__ flags)
{
    const float L2E = 1.4426950408889634f;
    int idx = blockIdx.x * 256 + threadIdx.x;   // grid covers H_*H_ = 65536
    {
        float s = isig[idx], m = imu[idx];
        unsigned a = __half_as_ushort(__float2half_rn(-s * L2E));
        unsigned b = __half_as_ushort(__float2half_rn(s * m * L2E));
        AB_i[idx] = a | (b << 16);
    }
    if (idx < (H_ / 2) * H_) {                  // W pairs: [i2][jg]
        int i2 = idx >> 8, jg = idx & 255;
        unsigned w0 = __half_as_ushort(__float2half_rn(iw[(2 * i2) * H_ + jg] * ierev[(2 * i2) * H_ + jg]));
        unsigned w1 = __half_as_ushort(__float2half_rn(iw[(2 * i2 + 1) * H_ + jg] * ierev[(2 * i2 + 1) * H_ + jg]));
        W2_i[idx] = w0 | (w1 << 16);
    }
    if (idx < I_ * H_) {
        float s = ssig[idx], m = smu[idx], w = sw[idx], e = serev[idx];
        unsigned a = __half_as_ushort(__float2half_rn(-s * L2E));
        unsigned b = __half_as_ushort(__float2half_rn(s * m * L2E));
        AB_s[idx] = a | (b << 16);
        WE_s[idx] = __half_as_ushort(__float2half_rn(w * e));
    }
    if (idx < NBLK * 16) flags[idx] = 0;
}

// ---------------- K1: recurrent LTC. 2 blocks per batch (j-split), paired via flags.
// block bx: batch b = bx & 127, j-half jh = bx >> 7, peer = bx ^ 128 (same XCD under %8 rr).
// 1024 threads = j(128) x c(8). Internal AB params LDS-resident (own j-half).
__global__ __launch_bounds__(1024) void ltc_rec(
    const float* __restrict__ x, const float* __restrict__ in_w, const float* __restrict__ in_b,
    const unsigned* __restrict__ AB_s, const unsigned short* __restrict__ WE_s,
    const unsigned* __restrict__ AB_i, const unsigned* __restrict__ W2_i,
    const float* __restrict__ vleak, const float* __restrict__ gleak, const float* __restrict__ cm,
    const float* __restrict__ out_w, const float* __restrict__ out_b,
    float* __restrict__ Vg, int* __restrict__ flags,
    float* __restrict__ out, float* __restrict__ hT)
{
    __shared__ unsigned ABl[H_ * 128];   // 128 KB: [i][j_local], fp16 A|B<<16
    __shared__ float Vs[H_];
    __shared__ float xs[I_];
    __shared__ float rn[8 * 128];
    __shared__ float rd[8 * 128];
    __shared__ float sn[128], sd[128];

    const int bx = blockIdx.x;
    const int b  = bx & 127;
    const int jh = bx >> 7;
    const int myf = bx << 4;
    const int pxf = (bx ^ 128) << 4;
    const int tid = threadIdx.x;
    const int j   = tid & 127;
    const int c   = tid >> 7;
    const int jg  = (jh << 7) + j;

    // stage own-half internal AB into LDS (coalesced)
    for (int k = tid; k < H_ * 128; k += 1024) {
        int i = k >> 7, jj = k & 127;
        ABl[k] = AB_i[(i << 8) + (jh << 7) + jj];
    }

    float cmt = 0.f, glvl = 0.f, dc = 0.f, owj = 0.f, obj = 0.f, iwv = 0.f, ibv = 0.f;
    if (tid < 128) {
        cmt = cm[jg] * (float)UF;
        float gl = gleak[jg];
        glvl = gl * vleak[jg];
        dc = cmt + gl + EPSF;
        owj = out_w[jg]; obj = out_b[jg];
        iwv = in_w[tid]; ibv = in_b[tid];
    }
    if (tid < H_) Vs[tid] = 0.f;
    __syncthreads();

    const float* xrow = x + (size_t)b * (T_ * I_);
    int p = 0;

    for (int t = 0; t < T_; ++t) {
        if (tid < I_) xs[tid] = fmaf(xrow[t * I_ + tid], iwv, ibv);
        __syncthreads();

        // ---- sensing: own jg, 16 i's per thread, streamed from L2
        {
            float pn = 0.f, pd = 0.f;
            const int i0 = c << 4;
            #pragma unroll
            for (int ii = 0; ii < 16; ++ii) {
                const int i = i0 + ii;
                unsigned ab = AB_s[(i << 8) + jg];
                float wv = __half2float(__ushort_as_half(WE_s[(i << 8) + jg]));
                float r  = rcpf(1.f + exp2f(fmaf(h2f_lo(ab), xs[i], h2f_hi(ab))));
                pn = fmaf(wv, r, pn);
                pd = fmaf(fabsf(wv), r, pd);
            }
            rn[(c << 7) + j] = pn; rd[(c << 7) + j] = pd;
        }
        __syncthreads();
        if (tid < 128) {
            float a = 0.f, d = 0.f;
            #pragma unroll
            for (int k = 0; k < 8; ++k) { a += rn[(k << 7) + j]; d += rd[(k << 7) + j]; }
            sn[j] = a; sd[j] = d;
        }
        __syncthreads();

        // ---- 6 unfolds with paired-block exchange
        for (int u = 0; u < UF; ++u) {
            float nm = 0.f, dn = 0.f;
            const int i0 = c << 5;
            #pragma unroll
            for (int ii = 0; ii < 32; ii += 4) {
                const int i = i0 + ii;
                const float4 v4 = *reinterpret_cast<const float4*>(Vs + i);
                unsigned w01 = W2_i[((i >> 1) << 8) + jg];
                unsigned w23 = W2_i[(((i >> 1) + 1) << 8) + jg];
                unsigned ab0 = ABl[((i + 0) << 7) + j];
                unsigned ab1 = ABl[((i + 1) << 7) + j];
                unsigned ab2 = ABl[((i + 2) << 7) + j];
                unsigned ab3 = ABl[((i + 3) << 7) + j];
                float r0 = rcpf(1.f + exp2f(fmaf(h2f_lo(ab0), v4.x, h2f_hi(ab0))));
                float r1 = rcpf(1.f + exp2f(fmaf(h2f_lo(ab1), v4.y, h2f_hi(ab1))));
                float r2 = rcpf(1.f + exp2f(fmaf(h2f_lo(ab2), v4.z, h2f_hi(ab2))));
                float r3 = rcpf(1.f + exp2f(fmaf(h2f_lo(ab3), v4.w, h2f_hi(ab3))));
                float w0 = h2f_lo(w01), w1 = h2f_hi(w01);
                float w2 = h2f_lo(w23), w3 = h2f_hi(w23);
                nm = fmaf(w0, r0, nm); dn = fmaf(fabsf(w0), r0, dn);
                nm = fmaf(w1, r1, nm); dn = fmaf(fabsf(w1), r1, dn);
                nm = fmaf(w2, r2, nm); dn = fmaf(fabsf(w2), r2, dn);
                nm = fmaf(w3, r3, nm); dn = fmaf(fabsf(w3), r3, dn);
            }
            rn[(c << 7) + j] = nm; rd[(c << 7) + j] = dn;
            __syncthreads();
            ++p;
            float* Vgb = Vg + (p & 1) * (B_ * H_) + (b << 8);
            if (tid < 128) {
                float N = sn[j], D = sd[j];
                #pragma unroll
                for (int k = 0; k < 8; ++k) { N += rn[(k << 7) + j]; D += rd[(k << 7) + j]; }
                float Vn = (fmaf(Vs[jg], cmt, glvl) + N) * rcpf(D + dc);
                Vs[jg] = Vn;
                __hip_atomic_store(Vgb + jg, Vn, __ATOMIC_RELAXED, __HIP_MEMORY_SCOPE_AGENT);
            }
            __syncthreads();
            if (tid == 0) {
                __hip_atomic_store(flags + myf, p, __ATOMIC_RELEASE, __HIP_MEMORY_SCOPE_AGENT);
                while (__hip_atomic_load(flags + pxf, __ATOMIC_ACQUIRE, __HIP_MEMORY_SCOPE_AGENT) < p) {}
            }
            __syncthreads();
            if (tid < 128) {
                const int pjg = ((jh ^ 1) << 7) + tid;
                Vs[pjg] = __hip_atomic_load(Vgb + pjg, __ATOMIC_RELAXED, __HIP_MEMORY_SCOPE_AGENT);
            }
            __syncthreads();
        }

        if (tid < 128) out[((size_t)b * T_ + t) * H_ + jg] = fmaf(Vs[jg], owj, obj);
    }
    if (tid < 128) hT[(b << 8) + jg] = Vs[jg];
}

extern "C" void kernel_launch(void* const* d_in, const int* in_sizes, int n_in,
                              void* d_out, int out_size, void* d_ws, size_t ws_size,
                              hipStream_t stream) {
    const float* x     = (const float*)d_in[0];
    const float* in_w  = (const float*)d_in[1];
    const float* in_b  = (const float*)d_in[2];
    const float* smu   = (const float*)d_in[3];
    const float* ssig  = (const float*)d_in[4];
    const float* sw    = (const float*)d_in[5];
    const float* serev = (const float*)d_in[6];
    const float* imu   = (const float*)d_in[7];
    const float* isig  = (const float*)d_in[8];
    const float* iw    = (const float*)d_in[9];
    const float* ierev = (const float*)d_in[10];
    const float* vleak = (const float*)d_in[11];
    const float* gleak = (const float*)d_in[12];
    const float* cmv   = (const float*)d_in[13];
    const float* ow    = (const float*)d_in[14];
    const float* ob    = (const float*)d_in[15];

    float* out = (float*)d_out;                 // [B, T, H]
    float* hT  = out + (size_t)B_ * T_ * H_;    // [B, H]

    char* w = (char*)d_ws;
    unsigned*       AB_i = (unsigned*)(w);                      // 256 KB  [i][jg]
    unsigned*       W2_i = (unsigned*)(w + (256 << 10));        // 128 KB  [i2][jg]
    unsigned*       AB_s = (unsigned*)(w + (384 << 10));        // 128 KB  [i][jg]
    unsigned short* WE_s = (unsigned short*)(w + (512 << 10));  //  64 KB  [i][jg]
    float*          Vg   = (float*)(w + (576 << 10));           // 256 KB  [2][B][H]
    int*            flags= (int*)(w + (832 << 10));             //  16 KB  [256][16]

    pack_params<<<dim3(H_ * H_ / 256), dim3(256), 0, stream>>>(
        smu, ssig, sw, serev, imu, isig, iw, ierev, AB_s, WE_s, AB_i, W2_i, flags);

    ltc_rec<<<dim3(NBLK), dim3(1024), 0, stream>>>(
        x, in_w, in_b, AB_s, WE_s, AB_i, W2_i, vleak, gleak, cmv, ow, ob,
        Vg, flags, out, hT);
}